// Round 9
// baseline (485.425 us; speedup 1.0000x reference)
//
#include <hip/hip_runtime.h>
#include <hip/hip_cooperative_groups.h>

namespace cg = cooperative_groups;

#define S_LEN 2048
#define HID   1280
#define NH    16
#define HD    80
#define WIN   64
#define NWIN  (S_LEN / WIN)

typedef _Float16 half4v __attribute__((ext_vector_type(4)));
typedef _Float16 half8v __attribute__((ext_vector_type(8)));
typedef float    float4v __attribute__((ext_vector_type(4)));

__device__ __forceinline__ void gload16(const _Float16* g, _Float16* l)
{
    __builtin_amdgcn_global_load_lds((const __attribute__((address_space(1))) void*)g,
                                     (__attribute__((address_space(3))) void*)l,
                                     16, 0, 0);
}

template <int N>
__device__ __forceinline__ void waitcnt_vm()
{
    if constexpr (N == 0)      asm volatile("s_waitcnt vmcnt(0)" ::: "memory");
    else if constexpr (N == 3) asm volatile("s_waitcnt vmcnt(3)" ::: "memory");
    else static_assert(N < 0, "add literal");
}

__device__ __forceinline__ void cfence() { asm volatile("" ::: "memory"); }

// ============================================================================
// mega kernel — grid-size agnostic (tile loops stride by gridDim.x).
// Phase 0: qkv_w cvt | sync | Phase 1: qkv GEMM | sync |
// Phase 2: attn(+RoPE) + projw cvt | sync | Phase 3: proj GEMM.
// ============================================================================
__global__ __launch_bounds__(512, 4) void mega(
    const float* __restrict__ hidden,
    const float* __restrict__ cosb,
    const float* __restrict__ sinb,
    const float* __restrict__ qkv_w,
    const float* __restrict__ qkv_b,
    const float* __restrict__ proj_w,
    const float* __restrict__ proj_b,
    _Float16* __restrict__ qkvw16,
    _Float16* __restrict__ projw16,
    _Float16* __restrict__ qkv16,
    _Float16* __restrict__ attn16,
    float* __restrict__ out)
{
    alignas(16) __shared__ _Float16 smem[33792];   // 67.6 KB union

    cg::grid_group grid = cg::this_grid();
    const int G    = gridDim.x;
    const int bid  = blockIdx.x;
    const int t    = threadIdx.x;
    const int lane = t & 63, wave = t >> 6;
    const int g    = lane >> 4, r = lane & 15;

    // ---------------- phase 0: qkv_w fp32 -> fp16 ----------------
    {
        const int n4 = 3 * HID * HID / 4;
        for (int i = bid * 512 + t; i < n4; i += G * 512) {
            float4v v = ((const float4v*)qkv_w)[i];
            half4v h;
#pragma unroll
            for (int j = 0; j < 4; j++) h[j] = (_Float16)v[j];
            ((half4v*)qkvw16)[i] = h;
        }
    }
    __threadfence();
    grid.sync();

    // ---------------- phase 1: qkv GEMM (128x128, BK=64, 8 waves 2x4) ----------------
    {
        constexpr int K = HID, N = 3 * HID, BK = 64;
        constexpr int MR = 4, NR = 2, CA = 2, CB = 2;
        constexpr int nt = K / BK;
        _Float16* As = smem;                 // [2][128*64]
        _Float16* Bs = smem + 16384;         // [2][128*64]

        const int wr = (wave >> 2) * 64, wc = (wave & 3) * 32;
        const int srow  = lane >> 3;
        const int lcol  = (lane & 7) * 8;
        const int scolB = ((lane & 7) ^ srow) * 8;
        const int wcol  = scolB;

        for (int tile = bid; tile < 480; tile += G) {
            const int row_a0 = (tile & 15) * 128, row_b0 = (tile >> 4) * 128;

            float4v acc[MR][NR];
            const float4v zero = {0.f, 0.f, 0.f, 0.f};
#pragma unroll
            for (int m = 0; m < MR; m++)
#pragma unroll
                for (int n = 0; n < NR; n++) acc[m][n] = zero;

            float4v a0[CA], a1[CA];
            auto issue = [&](int buf, int k0) {
#pragma unroll
                for (int i = 0; i < CA; i++) {
                    int c = wave * CA + i;
                    const float* src = &hidden[(size_t)(row_a0 + c * 8 + srow) * K + k0 + lcol];
                    a0[i] = *(const float4v*)src;
                    a1[i] = *(const float4v*)(src + 4);
                }
#pragma unroll
                for (int i = 0; i < CB; i++) {
                    int c = wave * CB + i;
                    gload16(&qkvw16[(size_t)(row_b0 + c * 8 + srow) * K + k0 + scolB],
                            &Bs[buf * 8192 + c * 512]);
                }
            };
            auto commitA = [&](int buf) {
#pragma unroll
                for (int i = 0; i < CA; i++) {
                    int c = wave * CA + i;
                    half8v h;
#pragma unroll
                    for (int j = 0; j < 4; j++) { h[j] = (_Float16)a0[i][j]; h[4 + j] = (_Float16)a1[i][j]; }
                    *(half8v*)&As[buf * 8192 + (c * 8 + srow) * 64 + wcol] = h;
                }
            };

            issue(0, 0);
            commitA(0);
            __syncthreads();

            int cur = 0;
            for (int t0 = 0; t0 < nt; t0++) {
                const bool pre = (t0 + 1 < nt);
                if (pre) { issue(cur ^ 1, (t0 + 1) * BK); cfence(); }

#pragma unroll
                for (int kc = 0; kc < 2; kc++) {
                    half8v af[MR], bf[NR];
#pragma unroll
                    for (int m = 0; m < MR; m++) {
                        int row = wr + m * 16 + r;
                        af[m] = *(const half8v*)&As[cur * 8192 + row * 64 + (((kc * 4 + g) ^ (r & 7)) * 8)];
                    }
#pragma unroll
                    for (int n = 0; n < NR; n++) {
                        int row = wc + n * 16 + r;
                        bf[n] = *(const half8v*)&Bs[cur * 8192 + row * 64 + (((kc * 4 + g) ^ (r & 7)) * 8)];
                    }
#pragma unroll
                    for (int m = 0; m < MR; m++)
#pragma unroll
                        for (int n = 0; n < NR; n++)
                            acc[m][n] = __builtin_amdgcn_mfma_f32_16x16x32_f16(af[m], bf[n], acc[m][n], 0, 0, 0);
                }
                if (pre) commitA(cur ^ 1);
                __syncthreads();
                cur ^= 1;
            }

#pragma unroll
            for (int m = 0; m < MR; m++)
#pragma unroll
                for (int n = 0; n < NR; n++) {
                    int col = row_b0 + wc + n * 16 + r;
                    float bv = qkv_b[col];
#pragma unroll
                    for (int i = 0; i < 4; i++) {
                        int row = row_a0 + wr + m * 16 + g * 4 + i;
                        qkv16[(size_t)row * N + col] = (_Float16)(acc[m][n][i] + bv);
                    }
                }
        }
    }
    __threadfence();
    grid.sync();

    // ---------------- phase 2: attn + RoPE (+ projw cvt) ----------------
    // pair i: waves 0-3 -> unit 2i, waves 4-7 -> unit 2i+1 (units = 512 total).
    {
        const int slab = wave >> 2;
        _Float16 (*Qs)[88] = (_Float16(*)[88])(smem + slab * 16896);
        _Float16 (*Ks)[88] = Qs + 64;
        _Float16 (*Vs)[88] = Ks + 64;
        const int t4 = t & 255;
        const int w4 = t4 >> 6;

        for (int ip = bid; ip < 256; ip += G) {
            const int u  = 2 * ip + slab;
            const int ww = u & 31, hh = u >> 5;
            const int s0 = ww * WIN;

#pragma unroll
            for (int i = 0; i < 5; i++) {
                int c = t4 + 256 * i;
                int row = c / 20, cc = (c % 20) * 4;
                int s = s0 + row;
                size_t base = (size_t)s * (3 * HID) + hh * HD;
                int pc = (cc < 40) ? cc + 40 : cc - 40;
                float sign = (cc < 40) ? -1.f : 1.f;
                half4v q  = *(const half4v*)&qkv16[base + cc];
                half4v qp = *(const half4v*)&qkv16[base + pc];
                half4v k  = *(const half4v*)&qkv16[base + HID + cc];
                half4v kp = *(const half4v*)&qkv16[base + HID + pc];
                half4v v  = *(const half4v*)&qkv16[base + 2 * HID + cc];
                float4v cs = *(const float4v*)&cosb[(size_t)s * HD + cc];
                float4v sn = *(const float4v*)&sinb[(size_t)s * HD + cc];
                half4v qo, ko;
#pragma unroll
                for (int j = 0; j < 4; j++) {
                    qo[j] = (_Float16)((float)q[j] * cs[j] + sign * (float)qp[j] * sn[j]);
                    ko[j] = (_Float16)((float)k[j] * cs[j] + sign * (float)kp[j] * sn[j]);
                }
                *(half4v*)&Qs[row][cc] = qo;
                *(half4v*)&Ks[row][cc] = ko;
                *(half4v*)&Vs[row][cc] = v;
            }
            __syncthreads();

            float4v sc[4];
            const float4v zero = {0.f, 0.f, 0.f, 0.f};
#pragma unroll
            for (int kt = 0; kt < 4; kt++) sc[kt] = zero;
#pragma unroll
            for (int hc = 0; hc < 5; hc++) {
                half4v qf = *(const half4v*)&Qs[w4 * 16 + r][hc * 16 + g * 4];
#pragma unroll
                for (int kt = 0; kt < 4; kt++) {
                    half4v kf = *(const half4v*)&Ks[kt * 16 + r][hc * 16 + g * 4];
                    sc[kt] = __builtin_amdgcn_mfma_f32_16x16x16f16(kf, qf, sc[kt], 0, 0, 0);
                }
            }

            const float scale = 0.11180339887498948f; // 1/sqrt(80)
            float mx = -1e30f;
#pragma unroll
            for (int kt = 0; kt < 4; kt++)
#pragma unroll
                for (int i = 0; i < 4; i++) { sc[kt][i] *= scale; mx = fmaxf(mx, sc[kt][i]); }
            mx = fmaxf(mx, __shfl_xor(mx, 16));
            mx = fmaxf(mx, __shfl_xor(mx, 32));
            float sum = 0.f;
#pragma unroll
            for (int kt = 0; kt < 4; kt++)
#pragma unroll
                for (int i = 0; i < 4; i++) { float e = __expf(sc[kt][i] - mx); sc[kt][i] = e; sum += e; }
            sum += __shfl_xor(sum, 16);
            sum += __shfl_xor(sum, 32);
            float inv = 1.f / sum;

            half4v pa[4];
#pragma unroll
            for (int kc = 0; kc < 4; kc++) {
                pa[kc][0] = (_Float16)(sc[kc][0] * inv);
                pa[kc][1] = (_Float16)(sc[kc][1] * inv);
                pa[kc][2] = (_Float16)(sc[kc][2] * inv);
                pa[kc][3] = (_Float16)(sc[kc][3] * inv);
            }

#pragma unroll
            for (int n = 0; n < 5; n++) {
                float4v o = zero;
#pragma unroll
                for (int kc = 0; kc < 4; kc++) {
                    half4v vf;
#pragma unroll
                    for (int j = 0; j < 4; j++) vf[j] = Vs[kc * 16 + g * 4 + j][n * 16 + r];
                    o = __builtin_amdgcn_mfma_f32_16x16x16f16(pa[kc], vf, o, 0, 0, 0);
                }
#pragma unroll
                for (int i = 0; i < 4; i++) {
                    int qrow = s0 + w4 * 16 + g * 4 + i;
                    attn16[(size_t)qrow * HID + hh * HD + n * 16 + r] = (_Float16)o[i];
                }
            }
            __syncthreads();   // LDS safe for next pair iteration
        }

        const int n4 = HID * HID / 4;
        for (int i = bid * 512 + t; i < n4; i += G * 512) {
            float4v v = ((const float4v*)proj_w)[i];
            half4v h;
#pragma unroll
            for (int j = 0; j < 4; j++) h[j] = (_Float16)v[j];
            ((half4v*)projw16)[i] = h;
        }
    }
    __threadfence();
    grid.sync();

    // ---------------- phase 3: proj GEMM (64x128, BK=64, 320 tiles) ----------------
    {
        constexpr int K = HID, N = HID, BK = 64;
        constexpr int MR = 2, NR = 2, CA = 1, CB = 2, CHUNKS = 3;
        constexpr int nt = K / BK;
        _Float16* As = smem;                 // [2][64*64]
        _Float16* Bs = smem + 8192;          // [2][128*64]

        const int wr = (wave >> 2) * 32, wc = (wave & 3) * 32;
        const int srow = lane >> 3;
        const int scol = ((lane & 7) ^ srow) * 8;

        for (int tile = bid; tile < 320; tile += G) {
            const int row_a0 = (tile & 31) * 64, row_b0 = (tile >> 5) * 128;

            auto stage = [&](int buf, int k0) {
#pragma unroll
                for (int i = 0; i < CA; i++) {
                    int c = wave * CA + i;
                    gload16(&attn16[(size_t)(row_a0 + c * 8 + srow) * K + k0 + scol],
                            &As[buf * 4096 + c * 512]);
                }
#pragma unroll
                for (int i = 0; i < CB; i++) {
                    int c = wave * CB + i;
                    gload16(&projw16[(size_t)(row_b0 + c * 8 + srow) * K + k0 + scol],
                            &Bs[buf * 8192 + c * 512]);
                }
            };

            float4v acc[MR][NR];
            const float4v zero = {0.f, 0.f, 0.f, 0.f};
#pragma unroll
            for (int m = 0; m < MR; m++)
#pragma unroll
                for (int n = 0; n < NR; n++) acc[m][n] = zero;

            stage(0, 0);

            int cur = 0;
            for (int t0 = 0; t0 < nt; t0++) {
                if (t0 + 1 < nt) {
                    stage(cur ^ 1, (t0 + 1) * BK);
                    waitcnt_vm<CHUNKS>();
                } else {
                    waitcnt_vm<0>();
                }
                __builtin_amdgcn_s_barrier();
                cfence();

#pragma unroll
                for (int kc = 0; kc < 2; kc++) {
                    half8v af[MR], bf[NR];
#pragma unroll
                    for (int m = 0; m < MR; m++) {
                        int row = wr + m * 16 + r;
                        af[m] = *(const half8v*)&As[cur * 4096 + row * 64 + (((kc * 4 + g) ^ (r & 7)) * 8)];
                    }
#pragma unroll
                    for (int n = 0; n < NR; n++) {
                        int row = wc + n * 16 + r;
                        bf[n] = *(const half8v*)&Bs[cur * 8192 + row * 64 + (((kc * 4 + g) ^ (r & 7)) * 8)];
                    }
#pragma unroll
                    for (int m = 0; m < MR; m++)
#pragma unroll
                        for (int n = 0; n < NR; n++)
                            acc[m][n] = __builtin_amdgcn_mfma_f32_16x16x32_f16(af[m], bf[n], acc[m][n], 0, 0, 0);
                }
                cfence();
                __builtin_amdgcn_s_barrier();
                cur ^= 1;
            }

#pragma unroll
            for (int m = 0; m < MR; m++)
#pragma unroll
                for (int n = 0; n < NR; n++) {
                    int col = row_b0 + wc + n * 16 + r;
                    float bv = proj_b[col];
#pragma unroll
                    for (int i = 0; i < 4; i++) {
                        int row = row_a0 + wr + m * 16 + g * 4 + i;
                        out[(size_t)row * N + col] = acc[m][n][i] + bv;
                    }
                }
        }
    }
}

// ============================================================================
// Fallback path — r7's verified 4-kernel pipeline (runs only if coop fails)
// ============================================================================
__global__ void cvt_one(const float* __restrict__ in, _Float16* __restrict__ out, int n4)
{
    int i = blockIdx.x * blockDim.x + threadIdx.x;
    if (i < n4) {
        float4v v = ((const float4v*)in)[i];
        half4v h;
        h[0] = (_Float16)v[0]; h[1] = (_Float16)v[1];
        h[2] = (_Float16)v[2]; h[3] = (_Float16)v[3];
        ((half4v*)out)[i] = h;
    }
}

__global__ __launch_bounds__(512) void gemm_qkv_fb(
    const float*    __restrict__ Af,
    const _Float16* __restrict__ Bh,
    const float*    __restrict__ bias,
    _Float16*       __restrict__ C)
{
    constexpr int K = HID, N = 3 * HID;
    constexpr int BM = 128, BK = 64;
    constexpr int MR = 4, NR = 2, CA = 2, CB = 2;
    __shared__ _Float16 As[2][BM * BK];
    __shared__ _Float16 Bs[2][BM * BK];

    const int t = threadIdx.x;
    const int lane = t & 63, wave = t >> 6;
    const int g = lane >> 4, r = lane & 15;
    const int wr = (wave >> 2) * 64, wc = (wave & 3) * 32;
    const int row_a0 = blockIdx.x * BM, row_b0 = blockIdx.y * BM;

    const int srow  = lane >> 3;
    const int lcol  = (lane & 7) * 8;
    const int scolB = ((lane & 7) ^ srow) * 8;
    const int wcol  = scolB;

    float4v acc[MR][NR];
    const float4v zero = {0.f, 0.f, 0.f, 0.f};
#pragma unroll
    for (int m = 0; m < MR; m++)
#pragma unroll
        for (int n = 0; n < NR; n++) acc[m][n] = zero;

    float4v a0[CA], a1[CA];
    auto issue = [&](int buf, int k0) {
#pragma unroll
        for (int i = 0; i < CA; i++) {
            int c = wave * CA + i;
            const float* src = &Af[(size_t)(row_a0 + c * 8 + srow) * K + k0 + lcol];
            a0[i] = *(const float4v*)src;
            a1[i] = *(const float4v*)(src + 4);
        }
#pragma unroll
        for (int i = 0; i < CB; i++) {
            int c = wave * CB + i;
            gload16(&Bh[(size_t)(row_b0 + c * 8 + srow) * K + k0 + scolB],
                    &Bs[buf][c * 512]);
        }
    };
    auto commitA = [&](int buf) {
#pragma unroll
        for (int i = 0; i < CA; i++) {
            int c = wave * CA + i;
            half8v h;
#pragma unroll
            for (int j = 0; j < 4; j++) { h[j] = (_Float16)a0[i][j]; h[4 + j] = (_Float16)a1[i][j]; }
            *(half8v*)&As[buf][(c * 8 + srow) * 64 + wcol] = h;
        }
    };

    issue(0, 0);
    commitA(0);
    __syncthreads();

    const int nt = K / 64;
    int cur = 0;
    for (int t0 = 0; t0 < nt; t0++) {
        const bool pre = (t0 + 1 < nt);
        if (pre) { issue(cur ^ 1, (t0 + 1) * 64); cfence(); }

#pragma unroll
        for (int kc = 0; kc < 2; kc++) {
            half8v af[MR], bf[NR];
#pragma unroll
            for (int m = 0; m < MR; m++) {
                int row = wr + m * 16 + r;
                af[m] = *(const half8v*)&As[cur][row * 64 + (((kc * 4 + g) ^ (r & 7)) * 8)];
            }
#pragma unroll
            for (int n = 0; n < NR; n++) {
                int row = wc + n * 16 + r;
                bf[n] = *(const half8v*)&Bs[cur][row * 64 + (((kc * 4 + g) ^ (r & 7)) * 8)];
            }
#pragma unroll
            for (int m = 0; m < MR; m++)
#pragma unroll
                for (int n = 0; n < NR; n++)
                    acc[m][n] = __builtin_amdgcn_mfma_f32_16x16x32_f16(af[m], bf[n], acc[m][n], 0, 0, 0);
        }
        if (pre) commitA(cur ^ 1);
        __syncthreads();
        cur ^= 1;
    }

#pragma unroll
    for (int m = 0; m < MR; m++)
#pragma unroll
        for (int n = 0; n < NR; n++) {
            int col = row_b0 + wc + n * 16 + r;
            float bv = bias[col];
#pragma unroll
            for (int i = 0; i < 4; i++) {
                int row = row_a0 + wr + m * 16 + g * 4 + i;
                C[(size_t)row * N + col] = (_Float16)(acc[m][n][i] + bv);
            }
        }
}

__global__ __launch_bounds__(512) void gemm_proj_fb(
    const _Float16* __restrict__ A,
    const _Float16* __restrict__ B,
    const float*    __restrict__ bias,
    float*          __restrict__ C)
{
    constexpr int K = HID, N = HID;
    constexpr int MR = 2, NR = 2, CA = 1, CB = 2, CHUNKS = 3;
    __shared__ _Float16 As[2][64 * 64];
    __shared__ _Float16 Bs[2][128 * 64];

    const int t = threadIdx.x;
    const int lane = t & 63, wave = t >> 6;
    const int g = lane >> 4, r = lane & 15;
    const int wr = (wave >> 2) * 32, wc = (wave & 3) * 32;
    const int row_a0 = blockIdx.x * 64, row_b0 = blockIdx.y * 128;

    const int srow = lane >> 3;
    const int scol = ((lane & 7) ^ srow) * 8;

    auto stage = [&](int buf, int k0) {
#pragma unroll
        for (int i = 0; i < CA; i++) {
            int c = wave * CA + i;
            gload16(&A[(size_t)(row_a0 + c * 8 + srow) * K + k0 + scol], &As[buf][c * 512]);
        }
#pragma unroll
        for (int i = 0; i < CB; i++) {
            int c = wave * CB + i;
            gload16(&B[(size_t)(row_b0 + c * 8 + srow) * K + k0 + scol], &Bs[buf][c * 512]);
        }
    };

    float4v acc[MR][NR];
    const float4v zero = {0.f, 0.f, 0.f, 0.f};
#pragma unroll
    for (int m = 0; m < MR; m++)
#pragma unroll
        for (int n = 0; n < NR; n++) acc[m][n] = zero;

    stage(0, 0);

    const int nt = K / 64;
    int cur = 0;
    for (int t0 = 0; t0 < nt; t0++) {
        if (t0 + 1 < nt) { stage(cur ^ 1, (t0 + 1) * 64); waitcnt_vm<CHUNKS>(); }
        else             { waitcnt_vm<0>(); }
        __builtin_amdgcn_s_barrier();
        cfence();

#pragma unroll
        for (int kc = 0; kc < 2; kc++) {
            half8v af[MR], bf[NR];
#pragma unroll
            for (int m = 0; m < MR; m++) {
                int row = wr + m * 16 + r;
                af[m] = *(const half8v*)&As[cur][row * 64 + (((kc * 4 + g) ^ (r & 7)) * 8)];
            }
#pragma unroll
            for (int n = 0; n < NR; n++) {
                int row = wc + n * 16 + r;
                bf[n] = *(const half8v*)&Bs[cur][row * 64 + (((kc * 4 + g) ^ (r & 7)) * 8)];
            }
#pragma unroll
            for (int m = 0; m < MR; m++)
#pragma unroll
                for (int n = 0; n < NR; n++)
                    acc[m][n] = __builtin_amdgcn_mfma_f32_16x16x32_f16(af[m], bf[n], acc[m][n], 0, 0, 0);
        }
        cfence();
        __builtin_amdgcn_s_barrier();
        cur ^= 1;
    }

#pragma unroll
    for (int m = 0; m < MR; m++)
#pragma unroll
        for (int n = 0; n < NR; n++) {
            int col = row_b0 + wc + n * 16 + r;
            float bv = bias[col];
#pragma unroll
            for (int i = 0; i < 4; i++) {
                int row = row_a0 + wr + m * 16 + g * 4 + i;
                C[(size_t)row * N + col] = acc[m][n][i] + bv;
            }
        }
}

__global__ __launch_bounds__(256) void attn_fb(const _Float16* __restrict__ qkv,
                                               const float* __restrict__ cosb,
                                               const float* __restrict__ sinb,
                                               _Float16* __restrict__ attn,
                                               const float* __restrict__ projw,
                                               _Float16* __restrict__ projw16)
{
    __shared__ _Float16 Qs[64][88], Ks[64][88], Vs[64][88];
    const int w = blockIdx.x, h = blockIdx.y;
    const int t = threadIdx.x, lane = t & 63, wave = t >> 6;
    const int g = lane >> 4, r = lane & 15;
    const int s0 = w * WIN;

#pragma unroll
    for (int i = 0; i < 5; i++) {
        int c = t + 256 * i;
        int row = c / 20, cc = (c % 20) * 4;
        int s = s0 + row;
        size_t base = (size_t)s * (3 * HID) + h * HD;
        int pc = (cc < 40) ? cc + 40 : cc - 40;
        float sign = (cc < 40) ? -1.f : 1.f;
        half4v q  = *(const half4v*)&qkv[base + cc];
        half4v qp = *(const half4v*)&qkv[base + pc];
        half4v k  = *(const half4v*)&qkv[base + HID + cc];
        half4v kp = *(const half4v*)&qkv[base + HID + pc];
        half4v v  = *(const half4v*)&qkv[base + 2 * HID + cc];
        float4v cs = *(const float4v*)&cosb[(size_t)s * HD + cc];
        float4v sn = *(const float4v*)&sinb[(size_t)s * HD + cc];
        half4v qo, ko;
#pragma unroll
        for (int j = 0; j < 4; j++) {
            qo[j] = (_Float16)((float)q[j] * cs[j] + sign * (float)qp[j] * sn[j]);
            ko[j] = (_Float16)((float)k[j] * cs[j] + sign * (float)kp[j] * sn[j]);
        }
        *(half4v*)&Qs[row][cc] = qo;
        *(half4v*)&Ks[row][cc] = ko;
        *(half4v*)&Vs[row][cc] = v;
    }
    __syncthreads();

    float4v sc[4];
    const float4v zero = {0.f, 0.f, 0.f, 0.f};
#pragma unroll
    for (int kt = 0; kt < 4; kt++) sc[kt] = zero;
#pragma unroll
    for (int hc = 0; hc < 5; hc++) {
        half4v qf = *(const half4v*)&Qs[wave * 16 + r][hc * 16 + g * 4];
#pragma unroll
        for (int kt = 0; kt < 4; kt++) {
            half4v kf = *(const half4v*)&Ks[kt * 16 + r][hc * 16 + g * 4];
            sc[kt] = __builtin_amdgcn_mfma_f32_16x16x16f16(kf, qf, sc[kt], 0, 0, 0);
        }
    }

    const float scale = 0.11180339887498948f;
    float mx = -1e30f;
#pragma unroll
    for (int kt = 0; kt < 4; kt++)
#pragma unroll
        for (int i = 0; i < 4; i++) { sc[kt][i] *= scale; mx = fmaxf(mx, sc[kt][i]); }
    mx = fmaxf(mx, __shfl_xor(mx, 16));
    mx = fmaxf(mx, __shfl_xor(mx, 32));
    float sum = 0.f;
#pragma unroll
    for (int kt = 0; kt < 4; kt++)
#pragma unroll
        for (int i = 0; i < 4; i++) { float e = __expf(sc[kt][i] - mx); sc[kt][i] = e; sum += e; }
    sum += __shfl_xor(sum, 16);
    sum += __shfl_xor(sum, 32);
    float inv = 1.f / sum;

    half4v pa[4];
#pragma unroll
    for (int kc = 0; kc < 4; kc++) {
        pa[kc][0] = (_Float16)(sc[kc][0] * inv);
        pa[kc][1] = (_Float16)(sc[kc][1] * inv);
        pa[kc][2] = (_Float16)(sc[kc][2] * inv);
        pa[kc][3] = (_Float16)(sc[kc][3] * inv);
    }

#pragma unroll
    for (int n = 0; n < 5; n++) {
        float4v o = zero;
#pragma unroll
        for (int kc = 0; kc < 4; kc++) {
            half4v vf;
#pragma unroll
            for (int j = 0; j < 4; j++) vf[j] = Vs[kc * 16 + g * 4 + j][n * 16 + r];
            o = __builtin_amdgcn_mfma_f32_16x16x16f16(pa[kc], vf, o, 0, 0, 0);
        }
#pragma unroll
        for (int i = 0; i < 4; i++) {
            int qrow = s0 + wave * 16 + g * 4 + i;
            attn[(size_t)qrow * HID + h * HD + n * 16 + r] = (_Float16)o[i];
        }
    }

    const int np4 = HID * HID / 4;
    const int bid = blockIdx.y * gridDim.x + blockIdx.x;
    const int stride = gridDim.x * gridDim.y * 256;
    for (int i = bid * 256 + t; i < np4; i += stride) {
        float4v v = ((const float4v*)projw)[i];
        half4v hh;
        hh[0] = (_Float16)v[0]; hh[1] = (_Float16)v[1];
        hh[2] = (_Float16)v[2]; hh[3] = (_Float16)v[3];
        ((half4v*)projw16)[i] = hh;
    }
}

// ---------------- launch ----------------
extern "C" void kernel_launch(void* const* d_in, const int* in_sizes, int n_in,
                              void* d_out, int out_size, void* d_ws, size_t ws_size,
                              hipStream_t stream)
{
    const float* hidden = (const float*)d_in[0];
    const float* cosb   = (const float*)d_in[1];
    const float* sinb   = (const float*)d_in[2];
    const float* qkv_w  = (const float*)d_in[3];
    const float* qkv_b  = (const float*)d_in[4];
    const float* proj_w = (const float*)d_in[5];
    const float* proj_b = (const float*)d_in[6];

    _Float16* qkvw16  = (_Float16*)d_ws;                       // 3840*1280
    _Float16* projw16 = qkvw16 + (size_t)3 * HID * HID;        // 1280*1280
    _Float16* qkv16   = projw16 + (size_t)HID * HID;           // 2048*3840
    _Float16* attn16  = qkv16 + (size_t)S_LEN * 3 * HID;       // 2048*1280
    float*    outp    = (float*)d_out;

    void* args[] = {
        (void*)&hidden, (void*)&cosb, (void*)&sinb,
        (void*)&qkv_w,  (void*)&qkv_b,
        (void*)&proj_w, (void*)&proj_b,
        (void*)&qkvw16, (void*)&projw16, (void*)&qkv16, (void*)&attn16,
        (void*)&outp
    };

    hipError_t e = hipLaunchCooperativeKernel((const void*)mega, dim3(480), dim3(512),
                                              args, 0, stream);
    if (e != hipSuccess) {
        (void)hipGetLastError();   // clear sticky error
        e = hipLaunchCooperativeKernel((const void*)mega, dim3(256), dim3(512),
                                       args, 0, stream);
    }
    if (e != hipSuccess) {
        (void)hipGetLastError();
        // fallback: r7's verified 4-kernel pipeline
        const int nb4 = 3 * HID * HID / 4;
        cvt_one<<<(nb4 + 255) / 256, 256, 0, stream>>>(qkv_w, qkvw16, nb4);
        gemm_qkv_fb<<<dim3(S_LEN / 128, 3 * HID / 128), 512, 0, stream>>>(
            hidden, qkvw16, qkv_b, qkv16);
        attn_fb<<<dim3(NWIN, NH), 256, 0, stream>>>(
            qkv16, cosb, sinb, attn16, proj_w, projw16);
        gemm_proj_fb<<<dim3(S_LEN / 64, HID / 128), 512, 0, stream>>>(
            attn16, projw16, proj_b, outp);
    }
}

// Round 10
// 69.298 us; speedup vs baseline: 7.0049x; 7.0049x over previous
//
#include <hip/hip_runtime.h>

#define S_LEN 2048
#define HID   1280
#define NH    16
#define HD    80
#define WIN   64
#define NWIN  (S_LEN / WIN)

typedef _Float16 half4v __attribute__((ext_vector_type(4)));
typedef _Float16 half8v __attribute__((ext_vector_type(8)));
typedef float    float4v __attribute__((ext_vector_type(4)));

__device__ __forceinline__ void gload16(const _Float16* g, _Float16* l)
{
    __builtin_amdgcn_global_load_lds((const __attribute__((address_space(1))) void*)g,
                                     (__attribute__((address_space(3))) void*)l,
                                     16, 0, 0);
}

template <int N>
__device__ __forceinline__ void waitcnt_vm()
{
    if constexpr (N == 0)      asm volatile("s_waitcnt vmcnt(0)" ::: "memory");
    else if constexpr (N == 3) asm volatile("s_waitcnt vmcnt(3)" ::: "memory");
    else static_assert(N < 0, "add literal");
}

__device__ __forceinline__ void cfence() { asm volatile("" ::: "memory"); }

// ---------------- qkv GEMM: C[2048][3840] = hidden_f32 * qkv_w_f32^T + bias ----------------
// 128x128 tile, BK=64, 512 thr (8 waves, 2x4). BOTH operands read as fp32 and
// converted during reg-staging (T14 issue-early/commit-late): global float4v x2
// -> cvt -> XOR-swizzled ds_write_b128. No cvt pre-pass, no fp16 weight copy.
// Swizzle: phys col16 = logical col16 ^ (row & 7) -> conflict-free ds_read_b128.
__global__ __launch_bounds__(512) void gemm_qkv(
    const float* __restrict__ Af,    // [2048][1280] fp32
    const float* __restrict__ Bf,    // [3840][1280] fp32
    const float* __restrict__ bias,
    _Float16*    __restrict__ C)     // [2048][3840]
{
    constexpr int K = HID, N = 3 * HID, BK = 64;
    constexpr int MR = 4, NR = 2, CA = 2, CB = 2;
    __shared__ _Float16 As[2][128 * BK];
    __shared__ _Float16 Bs[2][128 * BK];

    const int t = threadIdx.x;
    const int lane = t & 63, wave = t >> 6;
    const int g = lane >> 4, r = lane & 15;
    const int wr = (wave >> 2) * 64, wc = (wave & 3) * 32;
    const int row_a0 = blockIdx.x * 128, row_b0 = blockIdx.y * 128;

    const int srow = lane >> 3;                 // row within 8-row chunk
    const int lcol = (lane & 7) * 8;            // linear global col (elements)
    const int wcol = ((lane & 7) ^ srow) * 8;   // swizzled LDS col

    float4v acc[MR][NR];
    const float4v zero = {0.f, 0.f, 0.f, 0.f};
#pragma unroll
    for (int m = 0; m < MR; m++)
#pragma unroll
        for (int n = 0; n < NR; n++) acc[m][n] = zero;

    float4v a0[CA], a1[CA], b0[CB], b1[CB];
    auto issue = [&](int k0) {
#pragma unroll
        for (int i = 0; i < CA; i++) {
            int c = wave * CA + i;
            const float* src = &Af[(size_t)(row_a0 + c * 8 + srow) * K + k0 + lcol];
            a0[i] = *(const float4v*)src;
            a1[i] = *(const float4v*)(src + 4);
        }
#pragma unroll
        for (int i = 0; i < CB; i++) {
            int c = wave * CB + i;
            const float* src = &Bf[(size_t)(row_b0 + c * 8 + srow) * K + k0 + lcol];
            b0[i] = *(const float4v*)src;
            b1[i] = *(const float4v*)(src + 4);
        }
    };
    auto commit = [&](int buf) {
#pragma unroll
        for (int i = 0; i < CA; i++) {
            int c = wave * CA + i;
            half8v h;
#pragma unroll
            for (int j = 0; j < 4; j++) { h[j] = (_Float16)a0[i][j]; h[4 + j] = (_Float16)a1[i][j]; }
            *(half8v*)&As[buf][(c * 8 + srow) * 64 + wcol] = h;
        }
#pragma unroll
        for (int i = 0; i < CB; i++) {
            int c = wave * CB + i;
            half8v h;
#pragma unroll
            for (int j = 0; j < 4; j++) { h[j] = (_Float16)b0[i][j]; h[4 + j] = (_Float16)b1[i][j]; }
            *(half8v*)&Bs[buf][(c * 8 + srow) * 64 + wcol] = h;
        }
    };

    issue(0);
    commit(0);
    __syncthreads();

    const int nt = K / BK;
    int cur = 0;
    for (int t0 = 0; t0 < nt; t0++) {
        const bool pre = (t0 + 1 < nt);
        if (pre) { issue((t0 + 1) * BK); cfence(); }   // loads fly under compute

#pragma unroll
        for (int kc = 0; kc < 2; kc++) {
            half8v af[MR], bf[NR];
#pragma unroll
            for (int m = 0; m < MR; m++) {
                int row = wr + m * 16 + r;
                af[m] = *(const half8v*)&As[cur][row * 64 + (((kc * 4 + g) ^ (r & 7)) * 8)];
            }
#pragma unroll
            for (int n = 0; n < NR; n++) {
                int row = wc + n * 16 + r;
                bf[n] = *(const half8v*)&Bs[cur][row * 64 + (((kc * 4 + g) ^ (r & 7)) * 8)];
            }
#pragma unroll
            for (int m = 0; m < MR; m++)
#pragma unroll
                for (int n = 0; n < NR; n++)
                    acc[m][n] = __builtin_amdgcn_mfma_f32_16x16x32_f16(af[m], bf[n], acc[m][n], 0, 0, 0);
        }
        if (pre) commit(cur ^ 1);   // loads had full compute phase in flight
        __syncthreads();
        cur ^= 1;
    }

#pragma unroll
    for (int m = 0; m < MR; m++)
#pragma unroll
        for (int n = 0; n < NR; n++) {
            int col = row_b0 + wc + n * 16 + r;
            float bv = bias[col];
#pragma unroll
            for (int i = 0; i < 4; i++) {
                int row = row_a0 + wr + m * 16 + g * 4 + i;
                C[(size_t)row * N + col] = (_Float16)(acc[m][n][i] + bv);
            }
        }
}

// ---------------- proj GEMM (r7 verified structure) ----------------
__global__ __launch_bounds__(512) void gemm_proj(
    const _Float16* __restrict__ A,    // attn16 [2048][1280]
    const _Float16* __restrict__ B,    // projw16 [1280][1280]
    const float*    __restrict__ bias,
    float*          __restrict__ C)    // [2048][1280]
{
    constexpr int K = HID, N = HID;
    constexpr int MR = 2, NR = 2, CA = 1, CB = 2, CHUNKS = 3;
    __shared__ _Float16 As[2][64 * 64];
    __shared__ _Float16 Bs[2][128 * 64];

    const int t = threadIdx.x;
    const int lane = t & 63, wave = t >> 6;
    const int g = lane >> 4, r = lane & 15;
    const int wr = (wave >> 2) * 32, wc = (wave & 3) * 32;
    const int row_a0 = blockIdx.x * 64, row_b0 = blockIdx.y * 128;

    const int srow = lane >> 3;
    const int scol = ((lane & 7) ^ srow) * 8;

    auto stage = [&](int buf, int k0) {
#pragma unroll
        for (int i = 0; i < CA; i++) {
            int c = wave * CA + i;
            gload16(&A[(size_t)(row_a0 + c * 8 + srow) * K + k0 + scol], &As[buf][c * 512]);
        }
#pragma unroll
        for (int i = 0; i < CB; i++) {
            int c = wave * CB + i;
            gload16(&B[(size_t)(row_b0 + c * 8 + srow) * K + k0 + scol], &Bs[buf][c * 512]);
        }
    };

    float4v acc[MR][NR];
    const float4v zero = {0.f, 0.f, 0.f, 0.f};
#pragma unroll
    for (int m = 0; m < MR; m++)
#pragma unroll
        for (int n = 0; n < NR; n++) acc[m][n] = zero;

    stage(0, 0);

    const int nt = K / 64;
    int cur = 0;
    for (int t0 = 0; t0 < nt; t0++) {
        if (t0 + 1 < nt) { stage(cur ^ 1, (t0 + 1) * 64); waitcnt_vm<CHUNKS>(); }
        else             { waitcnt_vm<0>(); }
        __builtin_amdgcn_s_barrier();
        cfence();

#pragma unroll
        for (int kc = 0; kc < 2; kc++) {
            half8v af[MR], bf[NR];
#pragma unroll
            for (int m = 0; m < MR; m++) {
                int row = wr + m * 16 + r;
                af[m] = *(const half8v*)&As[cur][row * 64 + (((kc * 4 + g) ^ (r & 7)) * 8)];
            }
#pragma unroll
            for (int n = 0; n < NR; n++) {
                int row = wc + n * 16 + r;
                bf[n] = *(const half8v*)&Bs[cur][row * 64 + (((kc * 4 + g) ^ (r & 7)) * 8)];
            }
#pragma unroll
            for (int m = 0; m < MR; m++)
#pragma unroll
                for (int n = 0; n < NR; n++)
                    acc[m][n] = __builtin_amdgcn_mfma_f32_16x16x32_f16(af[m], bf[n], acc[m][n], 0, 0, 0);
        }
        cfence();
        __builtin_amdgcn_s_barrier();
        cur ^= 1;
    }

#pragma unroll
    for (int m = 0; m < MR; m++)
#pragma unroll
        for (int n = 0; n < NR; n++) {
            int col = row_b0 + wc + n * 16 + r;
            float bv = bias[col];
#pragma unroll
            for (int i = 0; i < 4; i++) {
                int row = row_a0 + wr + m * 16 + g * 4 + i;
                C[(size_t)row * N + col] = acc[m][n][i] + bv;
            }
        }
}

// ---------------- windowed attention + fused RoPE + proj_w cvt tail ----------------
__global__ __launch_bounds__(256) void attn_kernel(const _Float16* __restrict__ qkv,
                                                   const float* __restrict__ cosb,
                                                   const float* __restrict__ sinb,
                                                   _Float16* __restrict__ attn,
                                                   const float* __restrict__ projw,
                                                   _Float16* __restrict__ projw16)
{
    __shared__ _Float16 Qs[64][88], Ks[64][88], Vs[64][88];
    const int w = blockIdx.x, h = blockIdx.y;
    const int t = threadIdx.x, lane = t & 63, wave = t >> 6;
    const int g = lane >> 4, r = lane & 15;
    const int s0 = w * WIN;

#pragma unroll
    for (int i = 0; i < 5; i++) {
        int c = t + 256 * i;
        int row = c / 20, cc = (c % 20) * 4;
        int s = s0 + row;
        size_t base = (size_t)s * (3 * HID) + h * HD;
        int pc = (cc < 40) ? cc + 40 : cc - 40;
        float sign = (cc < 40) ? -1.f : 1.f;
        half4v q  = *(const half4v*)&qkv[base + cc];
        half4v qp = *(const half4v*)&qkv[base + pc];
        half4v k  = *(const half4v*)&qkv[base + HID + cc];
        half4v kp = *(const half4v*)&qkv[base + HID + pc];
        half4v v  = *(const half4v*)&qkv[base + 2 * HID + cc];
        float4v cs = *(const float4v*)&cosb[(size_t)s * HD + cc];
        float4v sn = *(const float4v*)&sinb[(size_t)s * HD + cc];
        half4v qo, ko;
#pragma unroll
        for (int j = 0; j < 4; j++) {
            qo[j] = (_Float16)((float)q[j] * cs[j] + sign * (float)qp[j] * sn[j]);
            ko[j] = (_Float16)((float)k[j] * cs[j] + sign * (float)kp[j] * sn[j]);
        }
        *(half4v*)&Qs[row][cc] = qo;
        *(half4v*)&Ks[row][cc] = ko;
        *(half4v*)&Vs[row][cc] = v;
    }
    __syncthreads();

    float4v sc[4];
    const float4v zero = {0.f, 0.f, 0.f, 0.f};
#pragma unroll
    for (int kt = 0; kt < 4; kt++) sc[kt] = zero;
#pragma unroll
    for (int hc = 0; hc < 5; hc++) {
        half4v qf = *(const half4v*)&Qs[wave * 16 + r][hc * 16 + g * 4];
#pragma unroll
        for (int kt = 0; kt < 4; kt++) {
            half4v kf = *(const half4v*)&Ks[kt * 16 + r][hc * 16 + g * 4];
            sc[kt] = __builtin_amdgcn_mfma_f32_16x16x16f16(kf, qf, sc[kt], 0, 0, 0);
        }
    }

    const float scale = 0.11180339887498948f;
    float mx = -1e30f;
#pragma unroll
    for (int kt = 0; kt < 4; kt++)
#pragma unroll
        for (int i = 0; i < 4; i++) { sc[kt][i] *= scale; mx = fmaxf(mx, sc[kt][i]); }
    mx = fmaxf(mx, __shfl_xor(mx, 16));
    mx = fmaxf(mx, __shfl_xor(mx, 32));
    float sum = 0.f;
#pragma unroll
    for (int kt = 0; kt < 4; kt++)
#pragma unroll
        for (int i = 0; i < 4; i++) { float e = __expf(sc[kt][i] - mx); sc[kt][i] = e; sum += e; }
    sum += __shfl_xor(sum, 16);
    sum += __shfl_xor(sum, 32);
    float inv = 1.f / sum;

    half4v pa[4];
#pragma unroll
    for (int kc = 0; kc < 4; kc++) {
        pa[kc][0] = (_Float16)(sc[kc][0] * inv);
        pa[kc][1] = (_Float16)(sc[kc][1] * inv);
        pa[kc][2] = (_Float16)(sc[kc][2] * inv);
        pa[kc][3] = (_Float16)(sc[kc][3] * inv);
    }

#pragma unroll
    for (int n = 0; n < 5; n++) {
        float4v o = zero;
#pragma unroll
        for (int kc = 0; kc < 4; kc++) {
            half4v vf;
#pragma unroll
            for (int j = 0; j < 4; j++) vf[j] = Vs[kc * 16 + g * 4 + j][n * 16 + r];
            o = __builtin_amdgcn_mfma_f32_16x16x16f16(pa[kc], vf, o, 0, 0, 0);
        }
#pragma unroll
        for (int i = 0; i < 4; i++) {
            int qrow = s0 + wave * 16 + g * 4 + i;
            attn[(size_t)qrow * HID + h * HD + n * 16 + r] = (_Float16)o[i];
        }
    }

    // proj_w fp32 -> fp16, hidden under attn (completes before proj via stream order)
    const int np4 = HID * HID / 4;
    const int bid = blockIdx.y * gridDim.x + blockIdx.x;
    const int stride = gridDim.x * gridDim.y * 256;
    for (int i = bid * 256 + t; i < np4; i += stride) {
        float4v v = ((const float4v*)projw)[i];
        half4v hh;
        hh[0] = (_Float16)v[0]; hh[1] = (_Float16)v[1];
        hh[2] = (_Float16)v[2]; hh[3] = (_Float16)v[3];
        ((half4v*)projw16)[i] = hh;
    }
}

// ---------------- launch: 3-kernel chain ----------------
extern "C" void kernel_launch(void* const* d_in, const int* in_sizes, int n_in,
                              void* d_out, int out_size, void* d_ws, size_t ws_size,
                              hipStream_t stream)
{
    const float* hidden = (const float*)d_in[0];
    const float* cosb   = (const float*)d_in[1];
    const float* sinb   = (const float*)d_in[2];
    const float* qkv_w  = (const float*)d_in[3];
    const float* qkv_b  = (const float*)d_in[4];
    const float* proj_w = (const float*)d_in[5];
    const float* proj_b = (const float*)d_in[6];

    _Float16* projw16 = (_Float16*)d_ws;                       // 1280*1280
    _Float16* qkv16   = projw16 + (size_t)HID * HID;           // 2048*3840
    _Float16* attn16  = qkv16 + (size_t)S_LEN * 3 * HID;       // 2048*1280

    // qkv: both operands fp32, cvt fused into staging. (16,30) = 480 blocks.
    gemm_qkv<<<dim3(S_LEN / 128, 3 * HID / 128), 512, 0, stream>>>(
        hidden, qkv_w, qkv_b, qkv16);

    attn_kernel<<<dim3(NWIN, NH), 256, 0, stream>>>(
        qkv16, cosb, sinb, attn16, proj_w, projw16);

    gemm_proj<<<dim3(S_LEN / 64, HID / 128), 512, 0, stream>>>(
        attn16, projw16, proj_b, (float*)d_out);
}